// Round 1
// baseline (1549.943 us; speedup 1.0000x reference)
//
#include <hip/hip_runtime.h>
#include <hip/hip_bf16.h>

typedef __attribute__((ext_vector_type(8))) short short8;
typedef __attribute__((ext_vector_type(4))) float f32x4;

#define TSTEPS 1000
#define BATCH  256
#define NIN    256
#define HID    128

__device__ __forceinline__ ushort f2bf(float f){
  union { float f; unsigned u; } v; v.f = f;
  unsigned r = v.u + 0x7fffu + ((v.u >> 16) & 1u);   // round-to-nearest-even
  return (ushort)(r >> 16);
}

__device__ __forceinline__ float sigmoidf_fast(float x){
  return 1.f/(1.f + __expf(-x));
}
__device__ __forceinline__ float tanhf_fast(float a){
  float x = fabsf(a);
  float e = __expf(2.f*x);          // no overflow path: e->inf => t->1
  float t = 1.f - 2.f/(e + 1.f);
  return copysignf(t, a);
}

// One block = one direction x 16 batch rows; 8 waves; wave w owns gate tiles
// {w, 8+w, 16+w} (r,z,n) covering h columns [16w, 16w+16).
__global__ __launch_bounds__(512) void gru_fused(
    const float* __restrict__ y_aux,
    const float* __restrict__ W_ih_f, const float* __restrict__ W_hh_f,
    const float* __restrict__ b_ih_f, const float* __restrict__ b_hh_f,
    const float* __restrict__ W_ih_b, const float* __restrict__ W_hh_b,
    const float* __restrict__ b_ih_b, const float* __restrict__ b_hh_b,
    float* __restrict__ out)
{
  const int blk  = blockIdx.x;      // 0..31
  const int dir  = blk >> 4;        // 0 fwd, 1 bwd
  const int b0   = (blk & 15) << 4; // batch tile base
  const int tid  = threadIdx.x;
  const int wave = tid >> 6;        // 0..7
  const int lane = tid & 63;
  const int lrow = lane & 15;       // A-frag M row / B-frag N row / C col
  const int lgrp = lane >> 4;       // k-group / C row group

  const float* Wih = dir ? W_ih_b : W_ih_f;
  const float* Whh = dir ? W_hh_b : W_hh_f;
  const float* bih = dir ? b_ih_b : b_ih_f;
  const float* bhh = dir ? b_hh_b : b_hh_f;

  // LDS: double-buffered h (bf16 shadow) and x tile. +8 bf16 row pad
  // -> ds_read_b128 hits the 8-cycle bank minimum.
  __shared__ __align__(16) ushort hbuf[2][16][136];
  __shared__ __align__(16) ushort xbuf[2][16][264];

  // ---- persistent weight fragments (bf16) in registers ----
  short8 wih_f[3][8];   // [r,z,n][kslice of 32]
  short8 whh_f[3][4];
  #pragma unroll
  for (int t3 = 0; t3 < 3; ++t3){
    const int g = t3*128 + wave*16 + lrow;      // gate row (B-operand N index)
    #pragma unroll
    for (int kk = 0; kk < 8; ++kk){
      const float* p = Wih + g*NIN + kk*32 + lgrp*8;
      short8 v;
      #pragma unroll
      for (int e = 0; e < 8; ++e) v[e] = (short)f2bf(p[e]);
      wih_f[t3][kk] = v;
    }
    #pragma unroll
    for (int kk = 0; kk < 4; ++kk){
      const float* p = Whh + g*HID + kk*32 + lgrp*8;
      short8 v;
      #pragma unroll
      for (int e = 0; e < 8; ++e) v[e] = (short)f2bf(p[e]);
      whh_f[t3][kk] = v;
    }
  }
  float bihv[3], bhhv[3];
  #pragma unroll
  for (int t3 = 0; t3 < 3; ++t3){
    const int g = t3*128 + wave*16 + lrow;      // == this lane's C column gate
    bihv[t3] = bih[g];
    bhhv[t3] = bhh[g];
  }

  // ---- init: h = 0, stage first x tile ----
  for (int i = tid; i < 2*16*136; i += 512) ((ushort*)hbuf)[i] = 0;
  {
    const int row = tid >> 5, f8 = tid & 31;
    const int t0  = dir ? (TSTEPS-1) : 0;
    const float* p = y_aux + (size_t)(b0+row)*(TSTEPS*NIN) + (size_t)t0*NIN + f8*8;
    short8 v;
    #pragma unroll
    for (int e = 0; e < 8; ++e) v[e] = (short)f2bf(p[e]);
    *(short8*)&xbuf[0][row][f8*8] = v;
  }
  __syncthreads();

  float hm[4] = {0.f, 0.f, 0.f, 0.f};          // fp32 master h, 4 rows owned
  const int hcol = wave*16 + lrow;
  float* outr = out + 8192;                    // rnn_output base

  for (int s = 0; s < TSTEPS; ++s){
    const int tt  = dir ? (TSTEPS-1-s) : s;
    const int cur = s & 1, nb = cur ^ 1;

    // prefetch next timestep's x rows into registers (hidden under MFMA)
    const int tn   = dir ? (tt-1) : (tt+1);
    const int prow = tid >> 5, pf8 = tid & 31;
    const bool more = (s < TSTEPS-1);
    float4 pa, pb;
    if (more){
      const float* p = y_aux + (size_t)(b0+prow)*(TSTEPS*NIN) + (size_t)tn*NIN + pf8*8;
      pa = *(const float4*)p;
      pb = *(const float4*)(p+4);
    }

    // ---- MFMA: gh (K=128) and xp (K=256), n-gate parts kept separate ----
    f32x4 a_rh = {0,0,0,0}, a_zh = {0,0,0,0}, a_nh = {0,0,0,0};
    f32x4 a_rx = {0,0,0,0}, a_zx = {0,0,0,0}, a_nx = {0,0,0,0};
    #pragma unroll
    for (int kk = 0; kk < 4; ++kk){
      short8 a = *(const short8*)&hbuf[cur][lrow][kk*32 + lgrp*8];
      a_rh = __builtin_amdgcn_mfma_f32_16x16x32_bf16(a, whh_f[0][kk], a_rh, 0,0,0);
      a_zh = __builtin_amdgcn_mfma_f32_16x16x32_bf16(a, whh_f[1][kk], a_zh, 0,0,0);
      a_nh = __builtin_amdgcn_mfma_f32_16x16x32_bf16(a, whh_f[2][kk], a_nh, 0,0,0);
    }
    #pragma unroll
    for (int kk = 0; kk < 8; ++kk){
      short8 a = *(const short8*)&xbuf[cur][lrow][kk*32 + lgrp*8];
      a_rx = __builtin_amdgcn_mfma_f32_16x16x32_bf16(a, wih_f[0][kk], a_rx, 0,0,0);
      a_zx = __builtin_amdgcn_mfma_f32_16x16x32_bf16(a, wih_f[1][kk], a_zx, 0,0,0);
      a_nx = __builtin_amdgcn_mfma_f32_16x16x32_bf16(a, wih_f[2][kk], a_nx, 0,0,0);
    }

    // ---- gates + h update + global store ----
    #pragma unroll
    for (int i = 0; i < 4; ++i){
      const float rp  = a_rh[i] + a_rx[i] + bihv[0] + bhhv[0];
      const float zp  = a_zh[i] + a_zx[i] + bihv[1] + bhhv[1];
      const float hnp = a_nh[i] + bhhv[2];
      const float xnp = a_nx[i] + bihv[2];
      const float r = sigmoidf_fast(rp);
      const float z = sigmoidf_fast(zp);
      const float n = tanhf_fast(fmaf(r, hnp, xnp));
      const float hv = n + z*(hm[i] - n);     // (1-z)n + z*h
      hm[i] = hv;
      outr[(size_t)tt*(BATCH*2*HID) + (size_t)(b0 + lgrp*4 + i)*(2*HID)
           + dir*HID + hcol] = hv;
      hbuf[nb][lgrp*4 + i][hcol] = f2bf(hv);
    }

    // write prefetched x into next buffer
    if (more){
      short8 v;
      v[0]=(short)f2bf(pa.x); v[1]=(short)f2bf(pa.y);
      v[2]=(short)f2bf(pa.z); v[3]=(short)f2bf(pa.w);
      v[4]=(short)f2bf(pb.x); v[5]=(short)f2bf(pb.y);
      v[6]=(short)f2bf(pb.z); v[7]=(short)f2bf(pb.w);
      *(short8*)&xbuf[nb][prow][pf8*8] = v;
    }
    __syncthreads();
  }
}

// mu_0 / log_var_0 heads: temp = [zeros(B,L), hn0], so only W[:, L:] matters.
__global__ void heads(const float* __restrict__ out_rnn,
    const float* __restrict__ W_mu, const float* __restrict__ b_mu,
    const float* __restrict__ W_lv, const float* __restrict__ b_lv,
    float* __restrict__ out)
{
  const int oid   = blockIdx.x*256 + threadIdx.x;  // 0..8191
  const int which = oid >> 12;
  const int r     = oid & 4095;
  const int b = r >> 4, j = r & 15;
  const float* W    = which ? W_lv : W_mu;
  const float* bias = which ? b_lv : b_mu;
  const float* h = out_rnn + b*256;                // hn0 row = rnn_output[0][b]
  const float* w = W + j*272 + 16;                 // skip the L zero columns
  float acc = bias[j];
  for (int c = 0; c < 256; c += 4){
    acc += h[c]*w[c] + h[c+1]*w[c+1] + h[c+2]*w[c+2] + h[c+3]*w[c+3];
  }
  out[(which << 12) + r] = acc;
}

extern "C" void kernel_launch(void* const* d_in, const int* in_sizes, int n_in,
                              void* d_out, int out_size, void* d_ws, size_t ws_size,
                              hipStream_t stream)
{
  const float* y    = (const float*)d_in[0];
  const float* Wihf = (const float*)d_in[1];
  const float* Whhf = (const float*)d_in[2];
  const float* bihf = (const float*)d_in[3];
  const float* bhhf = (const float*)d_in[4];
  const float* Wihb = (const float*)d_in[5];
  const float* Whhb = (const float*)d_in[6];
  const float* bihb = (const float*)d_in[7];
  const float* bhhb = (const float*)d_in[8];
  const float* Wmu  = (const float*)d_in[9];
  const float* bmu  = (const float*)d_in[10];
  const float* Wlv  = (const float*)d_in[11];
  const float* blv  = (const float*)d_in[12];
  float* out = (float*)d_out;

  gru_fused<<<dim3(32), dim3(512), 0, stream>>>(
      y, Wihf, Whhf, bihf, bhhf, Wihb, Whhb, bihb, bhhb, out);
  heads<<<dim3(32), dim3(256), 0, stream>>>(out + 8192, Wmu, bmu, Wlv, blv, out);
}

// Round 2
// 1116.991 us; speedup vs baseline: 1.3876x; 1.3876x over previous
//
#include <hip/hip_runtime.h>
#include <hip/hip_bf16.h>

typedef short bf16x8 __attribute__((ext_vector_type(8)));
typedef float f32x4  __attribute__((ext_vector_type(4)));

#define TSTEPS 1000
#define BATCH  256
#define NIN    256
#define HID    128
#define TC     25
#define XP_T_STRIDE 98304ll                       // ushorts per t = 16*8*64*12
#define XP_NEED (2ull*TSTEPS*XP_T_STRIDE*2ull)    // bytes = 393,216,000

__device__ __forceinline__ ushort f2bf(float f){
  union { float f; unsigned u; } v; v.f = f;
  unsigned r = v.u + 0x7fffu + ((v.u >> 16) & 1u);
  return (ushort)(r >> 16);
}
__device__ __forceinline__ uint pk2(float lo, float hi){
  __hip_bfloat162 h = __float22bfloat162_rn(make_float2(lo, hi));
  union { __hip_bfloat162 h; uint u; } c; c.h = h; return c.u;
}
__device__ __forceinline__ float bflo(uint w){ union{uint u;float f;}c; c.u = w<<16; return c.f; }
__device__ __forceinline__ float bfhi(uint w){ union{uint u;float f;}c; c.u = w & 0xffff0000u; return c.f; }

__device__ __forceinline__ float sigmoid_fast(float x){
  return __builtin_amdgcn_rcpf(1.f + __expf(-x));
}
__device__ __forceinline__ float tanh_fast(float a){
  const float e = __expf(2.f*fabsf(a));
  const float t = fmaf(-2.f, __builtin_amdgcn_rcpf(e + 1.f), 1.f);
  return copysignf(t, a);
}
__device__ __forceinline__ bf16x8 ld_w8(const float* p){
  union { uint u[4]; bf16x8 v; } c;
  c.u[0]=pk2(p[0],p[1]); c.u[1]=pk2(p[2],p[3]);
  c.u[2]=pk2(p[4],p[5]); c.u[3]=pk2(p[6],p[7]);
  return c.v;
}

// ============================================================================
// Parallel input-projection GEMM: xp[dir][t][btile][wave][lane][12] (bf16),
// exactly the per-lane MFMA C-fragment layout gru_rec consumes.
// Biases folded: r,z get b_ih+b_hh; n gets b_ih only.
// ============================================================================
__global__ __launch_bounds__(512) void xp_gemm(
    const float* __restrict__ y_aux,
    const float* __restrict__ Wf, const float* __restrict__ bihf, const float* __restrict__ bhhf,
    const float* __restrict__ Wb, const float* __restrict__ bihb, const float* __restrict__ bhhb,
    ushort* __restrict__ xp)
{
  const int nch = TSTEPS/TC;
  const int blk = blockIdx.x;
  const int dir = blk / (16*nch);
  const int rem = blk % (16*nch);
  const int btile = rem / nch;
  const int tch = rem % nch;
  const int b0 = btile*16;
  const int tid=threadIdx.x, wave=tid>>6, lane=tid&63, lrow=lane&15, lgrp=lane>>4;
  const float* Wih = dir? Wb : Wf;
  const float* bih = dir? bihb : bihf;
  const float* bhh = dir? bhhb : bhhf;

  __shared__ __align__(16) ushort xsh[2][16][264];

  bf16x8 wf[3][8];
  float bias[3];
  #pragma unroll
  for (int t3=0;t3<3;++t3){
    const int g = t3*128 + wave*16 + lrow;
    #pragma unroll
    for (int kk=0;kk<8;++kk)
      wf[t3][kk] = ld_w8(Wih + g*NIN + kk*32 + lgrp*8);
    bias[t3] = bih[g] + (t3<2 ? bhh[g] : 0.f);
  }

  const int row = tid>>5, f8 = tid&31;
  const float* xsrc = y_aux + (size_t)(b0+row)*(TSTEPS*NIN) + (size_t)(tch*TC)*NIN + f8*8;
  {
    float4 a = *(const float4*)xsrc;
    float4 b = *(const float4*)(xsrc+4);
    union{uint u[4]; bf16x8 v;} c;
    c.u[0]=pk2(a.x,a.y); c.u[1]=pk2(a.z,a.w); c.u[2]=pk2(b.x,b.y); c.u[3]=pk2(b.z,b.w);
    *(bf16x8*)&xsh[0][row][f8*8] = c.v;
  }
  __syncthreads();

  ushort* sp = xp + (size_t)dir*TSTEPS*XP_T_STRIDE + (size_t)(tch*TC)*XP_T_STRIDE
             + ((size_t)((btile*8 + wave)*64 + lane))*12;

  for (int k=0;k<TC;++k){
    const int cur=k&1, nxt=cur^1;
    const bool more = (k < TC-1);
    float4 pa, pb;
    if (more){
      const float* p = xsrc + (size_t)(k+1)*NIN;
      pa = *(const float4*)p;
      pb = *(const float4*)(p+4);
    }
    f32x4 a0={0,0,0,0}, a1={0,0,0,0}, a2={0,0,0,0};
    #pragma unroll
    for (int kk=0;kk<8;++kk){
      bf16x8 a = *(const bf16x8*)&xsh[cur][lrow][kk*32 + lgrp*8];
      a0 = __builtin_amdgcn_mfma_f32_16x16x32_bf16(a, wf[0][kk], a0, 0,0,0);
      a1 = __builtin_amdgcn_mfma_f32_16x16x32_bf16(a, wf[1][kk], a1, 0,0,0);
      a2 = __builtin_amdgcn_mfma_f32_16x16x32_bf16(a, wf[2][kk], a2, 0,0,0);
    }
    const uint d0=pk2(a0[0]+bias[0], a0[1]+bias[0]);
    const uint d1=pk2(a0[2]+bias[0], a0[3]+bias[0]);
    const uint d2=pk2(a1[0]+bias[1], a1[1]+bias[1]);
    const uint d3=pk2(a1[2]+bias[1], a1[3]+bias[1]);
    const uint d4=pk2(a2[0]+bias[2], a2[1]+bias[2]);
    const uint d5=pk2(a2[2]+bias[2], a2[3]+bias[2]);
    *(uint2*)(sp)   = make_uint2(d0,d1);
    *(uint2*)(sp+4) = make_uint2(d2,d3);
    *(uint2*)(sp+8) = make_uint2(d4,d5);
    sp += XP_T_STRIDE;
    if (more){
      union{uint u[4]; bf16x8 v;} c;
      c.u[0]=pk2(pa.x,pa.y); c.u[1]=pk2(pa.z,pa.w); c.u[2]=pk2(pb.x,pb.y); c.u[3]=pk2(pb.z,pb.w);
      *(bf16x8*)&xsh[nxt][row][f8*8] = c.v;
    }
    // raw barrier: drain only LDS; global stores/loads stay in flight
    asm volatile("s_waitcnt lgkmcnt(0)\n\ts_barrier" ::: "memory");
  }
}

// ============================================================================
// Serial recurrence: 32 blocks (dir x btile), 8 waves; wave w owns gate tiles
// {w, 8+w, 16+w} = (r,z,n) for h columns [16w,16w+16). Only K=128 h-MFMAs.
// ============================================================================
__global__ __launch_bounds__(512) void gru_rec(
    const ushort* __restrict__ xp,
    const float* __restrict__ Whhf, const float* __restrict__ bhhf,
    const float* __restrict__ Whhb, const float* __restrict__ bhhb,
    float* __restrict__ out)
{
  const int blk=blockIdx.x, dir=blk>>4, btile=blk&15, b0=btile<<4;
  const int tid=threadIdx.x, wave=tid>>6, lane=tid&63, lrow=lane&15, lgrp=lane>>4;
  const float* Whh = dir? Whhb : Whhf;
  const float* bhh = dir? bhhb : bhhf;

  __shared__ __align__(16) ushort hbuf[2][16][136];

  bf16x8 whh[3][4];
  #pragma unroll
  for (int t3=0;t3<3;++t3){
    const int g = t3*128 + wave*16 + lrow;
    #pragma unroll
    for (int kk=0;kk<4;++kk)
      whh[t3][kk] = ld_w8(Whh + g*HID + kk*32 + lgrp*8);
  }
  const int hcol = wave*16 + lrow;
  const float bh2 = bhh[256 + hcol];

  { ushort* hb=&hbuf[0][0][0]; for (int i=tid;i<16*136;i+=512) hb[i]=0; }

  const int tt0 = dir? (TSTEPS-1):0;
  const long long sdel = dir? -XP_T_STRIDE : XP_T_STRIDE;
  const ushort* xpp = xp + (size_t)dir*TSTEPS*XP_T_STRIDE + (size_t)tt0*XP_T_STRIDE
                    + ((size_t)((btile*8+wave)*64+lane))*12;
  uint2 qa = *(const uint2*)(xpp);      // r pre-acts (idx 0..3)
  uint2 qb = *(const uint2*)(xpp+4);    // z pre-acts (idx 4..7)
  uint2 qc = *(const uint2*)(xpp+8);    // n pre-acts (idx 8..11)

  float* op = out + 8192 + (size_t)tt0*(BATCH*2*HID)
            + (size_t)(b0 + lgrp*4)*(2*HID) + dir*HID + hcol;
  const long long odel = dir? -(long long)(BATCH*2*HID) : (long long)(BATCH*2*HID);

  float hm[4]={0,0,0,0};
  __syncthreads();

  for (int s=0;s<TSTEPS;++s){
    const int cur=s&1, nxt=cur^1;
    const bool more = (s<TSTEPS-1);
    const ushort* pn = xpp + sdel;
    uint2 pa_=qa, pb_=qb, pc_=qc;
    if (more){
      pa_ = *(const uint2*)(pn);
      pb_ = *(const uint2*)(pn+4);
      pc_ = *(const uint2*)(pn+8);
    }

    f32x4 ar={0,0,0,0}, az={0,0,0,0}, an={0,0,0,0};
    #pragma unroll
    for (int kk=0;kk<4;++kk){
      bf16x8 a = *(const bf16x8*)&hbuf[cur][lrow][kk*32 + lgrp*8];
      ar = __builtin_amdgcn_mfma_f32_16x16x32_bf16(a, whh[0][kk], ar, 0,0,0);
      az = __builtin_amdgcn_mfma_f32_16x16x32_bf16(a, whh[1][kk], az, 0,0,0);
      an = __builtin_amdgcn_mfma_f32_16x16x32_bf16(a, whh[2][kk], an, 0,0,0);
    }

    float hvv[4];
    {
      const float xr0=bflo(qa.x), xr1=bfhi(qa.x), xr2=bflo(qa.y), xr3=bfhi(qa.y);
      const float xz0=bflo(qb.x), xz1=bfhi(qb.x), xz2=bflo(qb.y), xz3=bfhi(qb.y);
      const float xn0=bflo(qc.x), xn1=bfhi(qc.x), xn2=bflo(qc.y), xn3=bfhi(qc.y);
      const float r0=sigmoid_fast(ar[0]+xr0), r1=sigmoid_fast(ar[1]+xr1);
      const float r2=sigmoid_fast(ar[2]+xr2), r3=sigmoid_fast(ar[3]+xr3);
      const float z0=sigmoid_fast(az[0]+xz0), z1=sigmoid_fast(az[1]+xz1);
      const float z2=sigmoid_fast(az[2]+xz2), z3=sigmoid_fast(az[3]+xz3);
      const float n0=tanh_fast(fmaf(r0, an[0]+bh2, xn0));
      const float n1=tanh_fast(fmaf(r1, an[1]+bh2, xn1));
      const float n2=tanh_fast(fmaf(r2, an[2]+bh2, xn2));
      const float n3=tanh_fast(fmaf(r3, an[3]+bh2, xn3));
      hvv[0]=n0 + z0*(hm[0]-n0); hvv[1]=n1 + z1*(hm[1]-n1);
      hvv[2]=n2 + z2*(hm[2]-n2); hvv[3]=n3 + z3*(hm[3]-n3);
    }
    hm[0]=hvv[0]; hm[1]=hvv[1]; hm[2]=hvv[2]; hm[3]=hvv[3];
    op[0*(2*HID)] = hvv[0];
    op[1*(2*HID)] = hvv[1];
    op[2*(2*HID)] = hvv[2];
    op[3*(2*HID)] = hvv[3];
    const uint p01 = pk2(hvv[0], hvv[1]);
    const uint p23 = pk2(hvv[2], hvv[3]);
    hbuf[nxt][lgrp*4+0][hcol] = (ushort)p01;
    hbuf[nxt][lgrp*4+1][hcol] = (ushort)(p01>>16);
    hbuf[nxt][lgrp*4+2][hcol] = (ushort)p23;
    hbuf[nxt][lgrp*4+3][hcol] = (ushort)(p23>>16);

    op += odel; xpp = pn; qa=pa_; qb=pb_; qc=pc_;
    // raw barrier: drain LDS only; global h-stores keep flying
    asm volatile("s_waitcnt lgkmcnt(0)\n\ts_barrier" ::: "memory");
  }
}

// ============================================================================
// Fallback fused kernel (round-1, used only if ws_size is too small)
// ============================================================================
__global__ __launch_bounds__(512) void gru_fused(
    const float* __restrict__ y_aux,
    const float* __restrict__ W_ih_f, const float* __restrict__ W_hh_f,
    const float* __restrict__ b_ih_f, const float* __restrict__ b_hh_f,
    const float* __restrict__ W_ih_b, const float* __restrict__ W_hh_b,
    const float* __restrict__ b_ih_b, const float* __restrict__ b_hh_b,
    float* __restrict__ out)
{
  const int blk  = blockIdx.x;
  const int dir  = blk >> 4;
  const int b0   = (blk & 15) << 4;
  const int tid  = threadIdx.x;
  const int wave = tid >> 6;
  const int lane = tid & 63;
  const int lrow = lane & 15;
  const int lgrp = lane >> 4;

  const float* Wih = dir ? W_ih_b : W_ih_f;
  const float* Whh = dir ? W_hh_b : W_hh_f;
  const float* bih = dir ? b_ih_b : b_ih_f;
  const float* bhh = dir ? b_hh_b : b_hh_f;

  __shared__ __align__(16) ushort hbuf[2][16][136];
  __shared__ __align__(16) ushort xbuf[2][16][264];

  bf16x8 wih_f[3][8];
  bf16x8 whh_f[3][4];
  #pragma unroll
  for (int t3 = 0; t3 < 3; ++t3){
    const int g = t3*128 + wave*16 + lrow;
    #pragma unroll
    for (int kk = 0; kk < 8; ++kk) wih_f[t3][kk] = ld_w8(Wih + g*NIN + kk*32 + lgrp*8);
    #pragma unroll
    for (int kk = 0; kk < 4; ++kk) whh_f[t3][kk] = ld_w8(Whh + g*HID + kk*32 + lgrp*8);
  }
  float bihv[3], bhhv[3];
  #pragma unroll
  for (int t3 = 0; t3 < 3; ++t3){
    const int g = t3*128 + wave*16 + lrow;
    bihv[t3] = bih[g];
    bhhv[t3] = bhh[g];
  }

  for (int i = tid; i < 2*16*136; i += 512) ((ushort*)hbuf)[i] = 0;
  {
    const int row = tid >> 5, f8 = tid & 31;
    const int t0  = dir ? (TSTEPS-1) : 0;
    const float* p = y_aux + (size_t)(b0+row)*(TSTEPS*NIN) + (size_t)t0*NIN + f8*8;
    union{uint u[4]; bf16x8 v;} c;
    float4 a = *(const float4*)p; float4 b = *(const float4*)(p+4);
    c.u[0]=pk2(a.x,a.y); c.u[1]=pk2(a.z,a.w); c.u[2]=pk2(b.x,b.y); c.u[3]=pk2(b.z,b.w);
    *(bf16x8*)&xbuf[0][row][f8*8] = c.v;
  }
  __syncthreads();

  float hm[4] = {0.f, 0.f, 0.f, 0.f};
  const int hcol = wave*16 + lrow;
  float* outr = out + 8192;

  for (int s = 0; s < TSTEPS; ++s){
    const int tt  = dir ? (TSTEPS-1-s) : s;
    const int cur = s & 1, nxt = cur ^ 1;
    const int tn   = dir ? (tt-1) : (tt+1);
    const int prow = tid >> 5, pf8 = tid & 31;
    const bool more = (s < TSTEPS-1);
    float4 pa, pb;
    if (more){
      const float* p = y_aux + (size_t)(b0+prow)*(TSTEPS*NIN) + (size_t)tn*NIN + pf8*8;
      pa = *(const float4*)p;
      pb = *(const float4*)(p+4);
    }

    f32x4 a_rh = {0,0,0,0}, a_zh = {0,0,0,0}, a_nh = {0,0,0,0};
    f32x4 a_rx = {0,0,0,0}, a_zx = {0,0,0,0}, a_nx = {0,0,0,0};
    #pragma unroll
    for (int kk = 0; kk < 4; ++kk){
      bf16x8 a = *(const bf16x8*)&hbuf[cur][lrow][kk*32 + lgrp*8];
      a_rh = __builtin_amdgcn_mfma_f32_16x16x32_bf16(a, whh_f[0][kk], a_rh, 0,0,0);
      a_zh = __builtin_amdgcn_mfma_f32_16x16x32_bf16(a, whh_f[1][kk], a_zh, 0,0,0);
      a_nh = __builtin_amdgcn_mfma_f32_16x16x32_bf16(a, whh_f[2][kk], a_nh, 0,0,0);
    }
    #pragma unroll
    for (int kk = 0; kk < 8; ++kk){
      bf16x8 a = *(const bf16x8*)&xbuf[cur][lrow][kk*32 + lgrp*8];
      a_rx = __builtin_amdgcn_mfma_f32_16x16x32_bf16(a, wih_f[0][kk], a_rx, 0,0,0);
      a_zx = __builtin_amdgcn_mfma_f32_16x16x32_bf16(a, wih_f[1][kk], a_zx, 0,0,0);
      a_nx = __builtin_amdgcn_mfma_f32_16x16x32_bf16(a, wih_f[2][kk], a_nx, 0,0,0);
    }

    #pragma unroll
    for (int i = 0; i < 4; ++i){
      const float rp  = a_rh[i] + a_rx[i] + bihv[0] + bhhv[0];
      const float zp  = a_zh[i] + a_zx[i] + bihv[1] + bhhv[1];
      const float hnp = a_nh[i] + bhhv[2];
      const float xnp = a_nx[i] + bihv[2];
      const float r = sigmoid_fast(rp);
      const float z = sigmoid_fast(zp);
      const float n = tanh_fast(fmaf(r, hnp, xnp));
      const float hv = n + z*(hm[i] - n);
      hm[i] = hv;
      outr[(size_t)tt*(BATCH*2*HID) + (size_t)(b0 + lgrp*4 + i)*(2*HID)
           + dir*HID + hcol] = hv;
      hbuf[nxt][lgrp*4 + i][hcol] = f2bf(hv);
    }

    if (more){
      union{uint u[4]; bf16x8 v;} c;
      c.u[0]=pk2(pa.x,pa.y); c.u[1]=pk2(pa.z,pa.w); c.u[2]=pk2(pb.x,pb.y); c.u[3]=pk2(pb.z,pb.w);
      *(bf16x8*)&xbuf[nxt][prow][pf8*8] = c.v;
    }
    __syncthreads();
  }
}

// mu_0 / log_var_0 heads: temp = [zeros(B,L), hn0], so only W[:, L:] matters.
__global__ void heads(const float* __restrict__ out_rnn,
    const float* __restrict__ W_mu, const float* __restrict__ b_mu,
    const float* __restrict__ W_lv, const float* __restrict__ b_lv,
    float* __restrict__ out)
{
  const int oid   = blockIdx.x*256 + threadIdx.x;
  const int which = oid >> 12;
  const int r     = oid & 4095;
  const int b = r >> 4, j = r & 15;
  const float* W    = which ? W_lv : W_mu;
  const float* bias = which ? b_lv : b_mu;
  const float* h = out_rnn + b*256;
  const float* w = W + j*272 + 16;
  float acc = bias[j];
  for (int c = 0; c < 256; c += 4){
    acc += h[c]*w[c] + h[c+1]*w[c+1] + h[c+2]*w[c+2] + h[c+3]*w[c+3];
  }
  out[(which << 12) + r] = acc;
}

extern "C" void kernel_launch(void* const* d_in, const int* in_sizes, int n_in,
                              void* d_out, int out_size, void* d_ws, size_t ws_size,
                              hipStream_t stream)
{
  const float* y    = (const float*)d_in[0];
  const float* Wihf = (const float*)d_in[1];
  const float* Whhf = (const float*)d_in[2];
  const float* bihf = (const float*)d_in[3];
  const float* bhhf = (const float*)d_in[4];
  const float* Wihb = (const float*)d_in[5];
  const float* Whhb = (const float*)d_in[6];
  const float* bihb = (const float*)d_in[7];
  const float* bhhb = (const float*)d_in[8];
  const float* Wmu  = (const float*)d_in[9];
  const float* bmu  = (const float*)d_in[10];
  const float* Wlv  = (const float*)d_in[11];
  const float* blv  = (const float*)d_in[12];
  float* out = (float*)d_out;

  if (ws_size >= (size_t)XP_NEED){
    ushort* xpw = (ushort*)d_ws;
    xp_gemm<<<dim3(2*16*(TSTEPS/TC)), dim3(512), 0, stream>>>(
        y, Wihf, bihf, bhhf, Wihb, bihb, bhhb, xpw);
    gru_rec<<<dim3(32), dim3(512), 0, stream>>>(
        xpw, Whhf, bhhf, Whhb, bhhb, out);
  } else {
    gru_fused<<<dim3(32), dim3(512), 0, stream>>>(
        y, Wihf, Whhf, bihf, bhhf, Wihb, Whhb, bihb, bhhb, out);
  }
  heads<<<dim3(32), dim3(256), 0, stream>>>(out + 8192, Wmu, bmu, Wlv, blv, out);
}

// Round 3
// 958.700 us; speedup vs baseline: 1.6167x; 1.1651x over previous
//
#include <hip/hip_runtime.h>
#include <hip/hip_bf16.h>

typedef short bf16x8 __attribute__((ext_vector_type(8)));
typedef float f32x4  __attribute__((ext_vector_type(4)));

#define TSTEPS 1000
#define BATCH  256
#define NIN    256
#define HID    128
#define TC     40
#define LOG2E  1.44269504088896f

// SoA xp: xp4 = uint4 region (r,z preacts), xp2 = uint2 region (n preacts).
// index = ((dir*TSTEPS + t)*8192 + gidx), gidx = (btile*8+wave)*64+lane.
#define GIDX_N 8192
#define XP4_ELEMS (2ull*TSTEPS*GIDX_N)            // uint4 count
#define XP2_OFF_BYTES (XP4_ELEMS*16ull)           // 262,144,000
#define XP_NEED (XP4_ELEMS*16ull + 2ull*TSTEPS*GIDX_N*8ull)   // 393,216,000

__device__ __forceinline__ ushort f2bf(float f){
  union { float f; unsigned u; } v; v.f = f;
  unsigned r = v.u + 0x7fffu + ((v.u >> 16) & 1u);
  return (ushort)(r >> 16);
}
__device__ __forceinline__ uint pk2(float lo, float hi){
  __hip_bfloat162 h = __float22bfloat162_rn(make_float2(lo, hi));
  union { __hip_bfloat162 h; uint u; } c; c.h = h; return c.u;
}
__device__ __forceinline__ float bflo(uint w){ union{uint u;float f;}c; c.u = w<<16; return c.f; }
__device__ __forceinline__ float bfhi(uint w){ union{uint u;float f;}c; c.u = w & 0xffff0000u; return c.f; }

__device__ __forceinline__ float sigmoid_fast(float x){
  return __builtin_amdgcn_rcpf(1.f + __expf(-x));
}
__device__ __forceinline__ float tanh_fast(float a){
  const float e = __expf(2.f*fabsf(a));
  const float t = fmaf(-2.f, __builtin_amdgcn_rcpf(e + 1.f), 1.f);
  return copysignf(t, a);
}
__device__ __forceinline__ bf16x8 ld_w8(const float* p){
  union { uint u[4]; bf16x8 v; } c;
  c.u[0]=pk2(p[0],p[1]); c.u[1]=pk2(p[2],p[3]);
  c.u[2]=pk2(p[4],p[5]); c.u[3]=pk2(p[6],p[7]);
  return c.v;
}
__device__ __forceinline__ bf16x8 ld_w8s(const float* p, float s){
  union { uint u[4]; bf16x8 v; } c;
  c.u[0]=pk2(p[0]*s,p[1]*s); c.u[1]=pk2(p[2]*s,p[3]*s);
  c.u[2]=pk2(p[4]*s,p[5]*s); c.u[3]=pk2(p[6]*s,p[7]*s);
  return c.v;
}

// ============================================================================
// Input-projection GEMM. Writes PRESCALED (x log2e) preacts, biases folded:
// r,z: (acc + bih + bhh)*log2e ; n: (acc + bih)*log2e.
// ============================================================================
__global__ __launch_bounds__(512) void xp_gemm(
    const float* __restrict__ y_aux,
    const float* __restrict__ Wf, const float* __restrict__ bihf, const float* __restrict__ bhhf,
    const float* __restrict__ Wb, const float* __restrict__ bihb, const float* __restrict__ bhhb,
    uint4* __restrict__ xp4, uint2* __restrict__ xp2)
{
  const int nch = TSTEPS/TC;
  const int blk = blockIdx.x;
  const int dir = blk / (16*nch);
  const int rem = blk % (16*nch);
  const int btile = rem / nch;
  const int tch = rem % nch;
  const int b0 = btile*16;
  const int tid=threadIdx.x, wave=tid>>6, lane=tid&63, lrow=lane&15, lgrp=lane>>4;
  const float* Wih = dir? Wb : Wf;
  const float* bih = dir? bihb : bihf;
  const float* bhh = dir? bhhb : bhhf;

  __shared__ __align__(16) ushort xsh[2][16][264];

  bf16x8 wf[3][8];
  float biass[3];
  #pragma unroll
  for (int t3=0;t3<3;++t3){
    const int g = t3*128 + wave*16 + lrow;
    #pragma unroll
    for (int kk=0;kk<8;++kk)
      wf[t3][kk] = ld_w8(Wih + g*NIN + kk*32 + lgrp*8);
    biass[t3] = LOG2E * (bih[g] + (t3<2 ? bhh[g] : 0.f));
  }

  const int row = tid>>5, f8 = tid&31;
  const float* xsrc = y_aux + (size_t)(b0+row)*(TSTEPS*NIN) + (size_t)(tch*TC)*NIN + f8*8;
  {
    float4 a = *(const float4*)xsrc;
    float4 b = *(const float4*)(xsrc+4);
    union{uint u[4]; bf16x8 v;} c;
    c.u[0]=pk2(a.x,a.y); c.u[1]=pk2(a.z,a.w); c.u[2]=pk2(b.x,b.y); c.u[3]=pk2(b.z,b.w);
    *(bf16x8*)&xsh[0][row][f8*8] = c.v;
  }
  __syncthreads();

  const size_t gbase = ((size_t)dir*TSTEPS + (size_t)(tch*TC))*GIDX_N
                     + (size_t)((btile*8 + wave)*64 + lane);
  uint4* s4 = xp4 + gbase;
  uint2* s2 = xp2 + gbase;

  for (int k=0;k<TC;++k){
    const int cur=k&1, nxt=cur^1;
    const bool more = (k < TC-1);
    float4 pa, pb;
    if (more){
      const float* p = xsrc + (size_t)(k+1)*NIN;
      pa = *(const float4*)p;
      pb = *(const float4*)(p+4);
    }
    f32x4 a0={0,0,0,0}, a1={0,0,0,0}, a2={0,0,0,0};
    #pragma unroll
    for (int kk=0;kk<8;++kk){
      bf16x8 a = *(const bf16x8*)&xsh[cur][lrow][kk*32 + lgrp*8];
      a0 = __builtin_amdgcn_mfma_f32_16x16x32_bf16(a, wf[0][kk], a0, 0,0,0);
      a1 = __builtin_amdgcn_mfma_f32_16x16x32_bf16(a, wf[1][kk], a1, 0,0,0);
      a2 = __builtin_amdgcn_mfma_f32_16x16x32_bf16(a, wf[2][kk], a2, 0,0,0);
    }
    uint4 o4;
    o4.x = pk2(fmaf(LOG2E,a0[0],biass[0]), fmaf(LOG2E,a0[1],biass[0]));
    o4.y = pk2(fmaf(LOG2E,a0[2],biass[0]), fmaf(LOG2E,a0[3],biass[0]));
    o4.z = pk2(fmaf(LOG2E,a1[0],biass[1]), fmaf(LOG2E,a1[1],biass[1]));
    o4.w = pk2(fmaf(LOG2E,a1[2],biass[1]), fmaf(LOG2E,a1[3],biass[1]));
    uint2 o2;
    o2.x = pk2(fmaf(LOG2E,a2[0],biass[2]), fmaf(LOG2E,a2[1],biass[2]));
    o2.y = pk2(fmaf(LOG2E,a2[2],biass[2]), fmaf(LOG2E,a2[3],biass[2]));
    *s4 = o4;  s4 += GIDX_N;
    *s2 = o2;  s2 += GIDX_N;
    if (more){
      union{uint u[4]; bf16x8 v;} c;
      c.u[0]=pk2(pa.x,pa.y); c.u[1]=pk2(pa.z,pa.w); c.u[2]=pk2(pb.x,pb.y); c.u[3]=pk2(pb.z,pb.w);
      *(bf16x8*)&xsh[nxt][row][f8*8] = c.v;
    }
    asm volatile("s_waitcnt lgkmcnt(0)\n\ts_barrier" ::: "memory");
  }
}

// ============================================================================
// Serial recurrence: 32 blocks (dir x btile), 8 waves. Whh held prescaled by
// log2e; xp preacts arrive prescaled, biases folded. Depth-2 prefetch,
// unconditional wrap-safe loads (stay inside the xp allocation).
// ============================================================================
__global__ __launch_bounds__(512) void gru_rec(
    const uint4* __restrict__ xp4, const uint2* __restrict__ xp2,
    const float* __restrict__ Whhf, const float* __restrict__ bhhf,
    const float* __restrict__ Whhb, const float* __restrict__ bhhb,
    float* __restrict__ out)
{
  const int blk=blockIdx.x, dir=blk>>4, btile=blk&15, b0=btile<<4;
  const int tid=threadIdx.x, wave=tid>>6, lane=tid&63, lrow=lane&15, lgrp=lane>>4;
  const float* Whh = dir? Whhb : Whhf;
  const float* bhh = dir? bhhb : bhhf;

  __shared__ __align__(16) ushort hbuf[2][16][136];

  bf16x8 whh[3][4];
  #pragma unroll
  for (int t3=0;t3<3;++t3){
    const int g = t3*128 + wave*16 + lrow;
    #pragma unroll
    for (int kk=0;kk<4;++kk)
      whh[t3][kk] = ld_w8s(Whh + g*HID + kk*32 + lgrp*8, LOG2E);
  }
  const int hcol = wave*16 + lrow;
  const float bh2s = LOG2E * bhh[256 + hcol];

  { ushort* hb=&hbuf[0][0][0]; for (int i=tid;i<16*136;i+=512) hb[i]=0; }

  const int tt0 = dir? (TSTEPS-1):0;
  const long long d4 = dir? -(long long)GIDX_N : (long long)GIDX_N;
  const size_t gbase = ((size_t)dir*TSTEPS + (size_t)tt0)*GIDX_N
                     + (size_t)((btile*8+wave)*64+lane);
  const uint4* q4p = xp4 + gbase;
  const uint2* q2p = xp2 + gbase;
  uint4 q40 = q4p[0], q41 = q4p[d4];
  uint2 q20 = q2p[0], q21 = q2p[d4];
  const uint4* f4 = q4p + 2*d4;
  const uint2* f2 = q2p + 2*d4;

  float* op = out + 8192 + (size_t)tt0*(BATCH*2*HID)
            + (size_t)(b0 + lgrp*4)*(2*HID) + dir*HID + hcol;
  const long long odel = dir? -(long long)(BATCH*2*HID) : (long long)(BATCH*2*HID);

  float hm[4]={0,0,0,0};
  __syncthreads();

  for (int s=0;s<TSTEPS;++s){
    const int cur=s&1, nxt=cur^1;
    // depth-2 prefetch (wrap-safe: stays inside xp4/xp2 allocations)
    uint4 q42 = *f4; f4 += d4;
    uint2 q22 = *f2; f2 += d4;

    f32x4 ar={0,0,0,0}, az={0,0,0,0}, an={0,0,0,0};
    #pragma unroll
    for (int kk=0;kk<4;++kk){
      bf16x8 a = *(const bf16x8*)&hbuf[cur][lrow][kk*32 + lgrp*8];
      ar = __builtin_amdgcn_mfma_f32_16x16x32_bf16(a, whh[0][kk], ar, 0,0,0);
      az = __builtin_amdgcn_mfma_f32_16x16x32_bf16(a, whh[1][kk], az, 0,0,0);
      an = __builtin_amdgcn_mfma_f32_16x16x32_bf16(a, whh[2][kk], an, 0,0,0);
    }

    float hv[4];
    {
      const float xr[4] = {bflo(q40.x),bfhi(q40.x),bflo(q40.y),bfhi(q40.y)};
      const float xz[4] = {bflo(q40.z),bfhi(q40.z),bflo(q40.w),bfhi(q40.w)};
      const float xn[4] = {bflo(q20.x),bfhi(q20.x),bflo(q20.y),bfhi(q20.y)};
      #pragma unroll
      for (int i=0;i<4;++i){
        // all preacts prescaled by log2e -> exp2-native gates
        const float r = __builtin_amdgcn_rcpf(1.f + __builtin_amdgcn_exp2f(-(ar[i]+xr[i])));
        const float z = __builtin_amdgcn_rcpf(1.f + __builtin_amdgcn_exp2f(-(az[i]+xz[i])));
        const float y  = fmaf(r, an[i]+bh2s, xn[i]);   // = log2e * tanh-arg
        const float y2 = y + y;
        const float e  = __builtin_amdgcn_exp2f(fabsf(y2));
        const float t  = fmaf(-2.f, __builtin_amdgcn_rcpf(e+1.f), 1.f);
        const float n  = copysignf(t, y);
        hv[i] = fmaf(z, hm[i]-n, n);
        hm[i] = hv[i];
      }
    }
    const uint p01 = pk2(hv[0],hv[1]);
    const uint p23 = pk2(hv[2],hv[3]);
    hbuf[nxt][lgrp*4+0][hcol] = (ushort)p01;
    hbuf[nxt][lgrp*4+1][hcol] = (ushort)(p01>>16);
    hbuf[nxt][lgrp*4+2][hcol] = (ushort)p23;
    hbuf[nxt][lgrp*4+3][hcol] = (ushort)(p23>>16);
    op[0]   = hv[0];
    op[256] = hv[1];
    op[512] = hv[2];
    op[768] = hv[3];
    op += odel;
    q40=q41; q41=q42; q20=q21; q21=q22;
    asm volatile("s_waitcnt lgkmcnt(0)\n\ts_barrier" ::: "memory");
  }
}

// ============================================================================
// Fallback fused kernel (used only if ws_size is too small)
// ============================================================================
__global__ __launch_bounds__(512) void gru_fused(
    const float* __restrict__ y_aux,
    const float* __restrict__ W_ih_f, const float* __restrict__ W_hh_f,
    const float* __restrict__ b_ih_f, const float* __restrict__ b_hh_f,
    const float* __restrict__ W_ih_b, const float* __restrict__ W_hh_b,
    const float* __restrict__ b_ih_b, const float* __restrict__ b_hh_b,
    float* __restrict__ out)
{
  const int blk  = blockIdx.x;
  const int dir  = blk >> 4;
  const int b0   = (blk & 15) << 4;
  const int tid  = threadIdx.x;
  const int wave = tid >> 6;
  const int lane = tid & 63;
  const int lrow = lane & 15;
  const int lgrp = lane >> 4;

  const float* Wih = dir ? W_ih_b : W_ih_f;
  const float* Whh = dir ? W_hh_b : W_hh_f;
  const float* bih = dir ? b_ih_b : b_ih_f;
  const float* bhh = dir ? b_hh_b : b_hh_f;

  __shared__ __align__(16) ushort hbuf[2][16][136];
  __shared__ __align__(16) ushort xbuf[2][16][264];

  bf16x8 wih_f[3][8];
  bf16x8 whh_f[3][4];
  #pragma unroll
  for (int t3 = 0; t3 < 3; ++t3){
    const int g = t3*128 + wave*16 + lrow;
    #pragma unroll
    for (int kk = 0; kk < 8; ++kk) wih_f[t3][kk] = ld_w8(Wih + g*NIN + kk*32 + lgrp*8);
    #pragma unroll
    for (int kk = 0; kk < 4; ++kk) whh_f[t3][kk] = ld_w8(Whh + g*HID + kk*32 + lgrp*8);
  }
  float bihv[3], bhhv[3];
  #pragma unroll
  for (int t3 = 0; t3 < 3; ++t3){
    const int g = t3*128 + wave*16 + lrow;
    bihv[t3] = bih[g];
    bhhv[t3] = bhh[g];
  }

  for (int i = tid; i < 2*16*136; i += 512) ((ushort*)hbuf)[i] = 0;
  {
    const int row = tid >> 5, f8 = tid & 31;
    const int t0  = dir ? (TSTEPS-1) : 0;
    const float* p = y_aux + (size_t)(b0+row)*(TSTEPS*NIN) + (size_t)t0*NIN + f8*8;
    union{uint u[4]; bf16x8 v;} c;
    float4 a = *(const float4*)p; float4 b = *(const float4*)(p+4);
    c.u[0]=pk2(a.x,a.y); c.u[1]=pk2(a.z,a.w); c.u[2]=pk2(b.x,b.y); c.u[3]=pk2(b.z,b.w);
    *(bf16x8*)&xbuf[0][row][f8*8] = c.v;
  }
  __syncthreads();

  float hm[4] = {0.f, 0.f, 0.f, 0.f};
  const int hcol = wave*16 + lrow;
  float* outr = out + 8192;

  for (int s = 0; s < TSTEPS; ++s){
    const int tt  = dir ? (TSTEPS-1-s) : s;
    const int cur = s & 1, nxt = cur ^ 1;
    const int tn   = dir ? (tt-1) : (tt+1);
    const int prow = tid >> 5, pf8 = tid & 31;
    const bool more = (s < TSTEPS-1);
    float4 pa, pb;
    if (more){
      const float* p = y_aux + (size_t)(b0+prow)*(TSTEPS*NIN) + (size_t)tn*NIN + pf8*8;
      pa = *(const float4*)p;
      pb = *(const float4*)(p+4);
    }

    f32x4 a_rh = {0,0,0,0}, a_zh = {0,0,0,0}, a_nh = {0,0,0,0};
    f32x4 a_rx = {0,0,0,0}, a_zx = {0,0,0,0}, a_nx = {0,0,0,0};
    #pragma unroll
    for (int kk = 0; kk < 4; ++kk){
      bf16x8 a = *(const bf16x8*)&hbuf[cur][lrow][kk*32 + lgrp*8];
      a_rh = __builtin_amdgcn_mfma_f32_16x16x32_bf16(a, whh_f[0][kk], a_rh, 0,0,0);
      a_zh = __builtin_amdgcn_mfma_f32_16x16x32_bf16(a, whh_f[1][kk], a_zh, 0,0,0);
      a_nh = __builtin_amdgcn_mfma_f32_16x16x32_bf16(a, whh_f[2][kk], a_nh, 0,0,0);
    }
    #pragma unroll
    for (int kk = 0; kk < 8; ++kk){
      bf16x8 a = *(const bf16x8*)&xbuf[cur][lrow][kk*32 + lgrp*8];
      a_rx = __builtin_amdgcn_mfma_f32_16x16x32_bf16(a, wih_f[0][kk], a_rx, 0,0,0);
      a_zx = __builtin_amdgcn_mfma_f32_16x16x32_bf16(a, wih_f[1][kk], a_zx, 0,0,0);
      a_nx = __builtin_amdgcn_mfma_f32_16x16x32_bf16(a, wih_f[2][kk], a_nx, 0,0,0);
    }

    #pragma unroll
    for (int i = 0; i < 4; ++i){
      const float rp  = a_rh[i] + a_rx[i] + bihv[0] + bhhv[0];
      const float zp  = a_zh[i] + a_zx[i] + bihv[1] + bhhv[1];
      const float hnp = a_nh[i] + bhhv[2];
      const float xnp = a_nx[i] + bihv[2];
      const float r = sigmoid_fast(rp);
      const float z = sigmoid_fast(zp);
      const float n = tanh_fast(fmaf(r, hnp, xnp));
      const float hv = n + z*(hm[i] - n);
      hm[i] = hv;
      outr[(size_t)tt*(BATCH*2*HID) + (size_t)(b0 + lgrp*4 + i)*(2*HID)
           + dir*HID + hcol] = hv;
      hbuf[nxt][lgrp*4 + i][hcol] = f2bf(hv);
    }

    if (more){
      union{uint u[4]; bf16x8 v;} c;
      c.u[0]=pk2(pa.x,pa.y); c.u[1]=pk2(pa.z,pa.w); c.u[2]=pk2(pb.x,pb.y); c.u[3]=pk2(pb.z,pb.w);
      *(bf16x8*)&xbuf[nxt][prow][pf8*8] = c.v;
    }
    __syncthreads();
  }
}

// mu_0 / log_var_0 heads: temp = [zeros(B,L), hn0], so only W[:, L:] matters.
__global__ void heads(const float* __restrict__ out_rnn,
    const float* __restrict__ W_mu, const float* __restrict__ b_mu,
    const float* __restrict__ W_lv, const float* __restrict__ b_lv,
    float* __restrict__ out)
{
  const int oid   = blockIdx.x*256 + threadIdx.x;
  const int which = oid >> 12;
  const int r     = oid & 4095;
  const int b = r >> 4, j = r & 15;
  const float* W    = which ? W_lv : W_mu;
  const float* bias = which ? b_lv : b_mu;
  const float* h = out_rnn + b*256;
  const float* w = W + j*272 + 16;
  float acc = bias[j];
  for (int c = 0; c < 256; c += 4){
    acc += h[c]*w[c] + h[c+1]*w[c+1] + h[c+2]*w[c+2] + h[c+3]*w[c+3];
  }
  out[(which << 12) + r] = acc;
}

extern "C" void kernel_launch(void* const* d_in, const int* in_sizes, int n_in,
                              void* d_out, int out_size, void* d_ws, size_t ws_size,
                              hipStream_t stream)
{
  const float* y    = (const float*)d_in[0];
  const float* Wihf = (const float*)d_in[1];
  const float* Whhf = (const float*)d_in[2];
  const float* bihf = (const float*)d_in[3];
  const float* bhhf = (const float*)d_in[4];
  const float* Wihb = (const float*)d_in[5];
  const float* Whhb = (const float*)d_in[6];
  const float* bihb = (const float*)d_in[7];
  const float* bhhb = (const float*)d_in[8];
  const float* Wmu  = (const float*)d_in[9];
  const float* bmu  = (const float*)d_in[10];
  const float* Wlv  = (const float*)d_in[11];
  const float* blv  = (const float*)d_in[12];
  float* out = (float*)d_out;

  if (ws_size >= (size_t)XP_NEED){
    uint4* xp4 = (uint4*)d_ws;
    uint2* xp2 = (uint2*)((char*)d_ws + XP2_OFF_BYTES);
    xp_gemm<<<dim3(2*16*(TSTEPS/TC)), dim3(512), 0, stream>>>(
        y, Wihf, bihf, bhhf, Wihb, bihb, bhhb, xp4, xp2);
    gru_rec<<<dim3(32), dim3(512), 0, stream>>>(
        xp4, xp2, Whhf, bhhf, Whhb, bhhb, out);
  } else {
    gru_fused<<<dim3(32), dim3(512), 0, stream>>>(
        y, Wihf, Whhf, bihf, bhhf, Wihb, Whhb, bihb, bhhb, out);
  }
  heads<<<dim3(32), dim3(256), 0, stream>>>(out + 8192, Wmu, bmu, Wlv, blv, out);
}